// Round 5
// baseline (2402.953 us; speedup 1.0000x reference)
//
#include <hip/hip_runtime.h>

#define TS 100
#define NB 1024
#define NF 784
#define NH 200
#define NO 10
#define BT 4              // batch rows per block
#define TT 4              // timesteps per group
#define NG (TS / TT)      // 25 groups

// One block = 256 threads = 4 waves, owns batch rows bBase..bBase+3 for all T.
// Per 4-step group: stage x in LDS -> per-thread (h=tid<200) z-GEMM into regs
// -> 4 in-register LIF steps -> spikes to LDS -> per-wave Wout reduce + LI.
// No workspace. Only writes: d_out (every element, every call).
//
// NUMERICS CONTRACT (matches round-1 kernel that passed absmax 1.95e-3):
//  - z chain: acc=0; fmaf over k=0..783 strictly ascending; z = acc + bias
//  - LIF: vd = fmaf(0.1f, cu-v, v); spk = vd>1; v=(1-spk)*vd; cu = fmaf(0.8f,cu,z)
//  - LI:  vn = fmaf(0.1f, ili-vli, vli); ili = fmaf(0.8f, ili, ps)
// Do NOT reorder these chains; spike threshold is a cliff (1-ULP flips cost 5e-2).
__global__ __launch_bounds__(256) void fused_kernel(
    const float* __restrict__ x, const float* __restrict__ W0,
    const float* __restrict__ b0, const float* __restrict__ Wout,
    float* __restrict__ out)
{
    __shared__ float xs[BT][TT][NF];       // 50 KB, [bi][t][k]
    __shared__ float spkLds[TT][BT][256];  // 16 KB

    const int tid   = threadIdx.x;
    const int lane  = tid & 63;
    const int wv    = tid >> 6;            // wave id = batch row in reduce phase
    const int bBase = blockIdx.x * BT;

    // LIF state for hidden unit h = tid (tid < NH), batches bBase+0..3
    float v[BT], cu[BT];
    #pragma unroll
    for (int bi = 0; bi < BT; ++bi) { v[bi] = 0.f; cu[bi] = 0.f; }
    const float bias_h = (tid < NH) ? b0[tid] : 0.f;

    // lane-based Wout fragments for the reduce phase (h = lane + 64*s)
    float wo[4][NO];
    bool  hv[4];
    #pragma unroll
    for (int s = 0; s < 4; ++s) {
        const int h = lane + 64 * s;
        hv[s] = (h < NH);
        #pragma unroll
        for (int o = 0; o < NO; ++o)
            wo[s][o] = hv[s] ? Wout[o * NH + h] : 0.f;
    }
    // LI state (meaningful on lane < NO of each wave; batch = bBase+wv)
    float vli = 0.f, ili = 0.f;

    for (int g = 0; g < NG; ++g) {
        // ---- stage x[g*TT..+TT)[bBase..+BT)[784] into LDS (coalesced b128) --
        for (int idx = tid; idx < BT * TT * (NF / 4); idx += 256) {
            const int bi = idx / (TT * (NF / 4));
            const int r  = idx - bi * (TT * (NF / 4));
            const int j  = r / (NF / 4);
            const int kq = r - j * (NF / 4);
            const float4 xv = *(const float4*)&x[
                ((size_t)(g * TT + j) * NB + (bBase + bi)) * NF + 4 * kq];
            *(float4*)&xs[bi][j][4 * kq] = xv;
        }
        __syncthreads();

        // ---- z GEMM: acc from 0, strictly serial ascending-k fmaf chain ----
        if (tid < NH) {
            float acc[TT][BT];
            #pragma unroll
            for (int t = 0; t < TT; ++t)
                #pragma unroll
                for (int bi = 0; bi < BT; ++bi) acc[t][bi] = 0.f;

            const float* wrow = W0 + (size_t)tid * NF;
            #pragma unroll 4
            for (int kq = 0; kq < NF / 4; ++kq) {
                const float4 w4 = *(const float4*)&wrow[4 * kq];
                #pragma unroll
                for (int bi = 0; bi < BT; ++bi)
                    #pragma unroll
                    for (int t = 0; t < TT; ++t) {
                        const float4 x4 = *(const float4*)&xs[bi][t][4 * kq];
                        float a = acc[t][bi];
                        a = fmaf(w4.x, x4.x, a);
                        a = fmaf(w4.y, x4.y, a);
                        a = fmaf(w4.z, x4.z, a);
                        a = fmaf(w4.w, x4.w, a);
                        acc[t][bi] = a;
                    }
            }
            // ---- 4 LIF steps in registers (bias added HERE, round-1 order) --
            #pragma unroll
            for (int t = 0; t < TT; ++t)
                #pragma unroll
                for (int bi = 0; bi < BT; ++bi) {
                    const float z   = acc[t][bi] + bias_h;          // fl(acc+b)
                    const float vd  = fmaf(0.1f, cu[bi] - v[bi], v[bi]);
                    const float spk = vd > 1.0f ? 1.0f : 0.0f;
                    v[bi]  = (1.0f - spk) * vd;
                    cu[bi] = fmaf(0.8f, cu[bi], z);
                    spkLds[t][bi][tid] = spk;
                }
        }
        __syncthreads();

        // ---- spk @ Wout.T + LI; wave wv handles batch row bBase+wv ----
        for (int t = 0; t < TT; ++t) {
            float p[NO];
            #pragma unroll
            for (int o = 0; o < NO; ++o) p[o] = 0.f;
            #pragma unroll
            for (int s = 0; s < 4; ++s) {
                if (hv[s]) {
                    const float sv = spkLds[t][wv][lane + 64 * s];
                    #pragma unroll
                    for (int o = 0; o < NO; ++o)
                        p[o] = fmaf(sv, wo[s][o], p[o]);
                }
            }
            #pragma unroll
            for (int m = 1; m < 64; m <<= 1)
                #pragma unroll
                for (int o = 0; o < NO; ++o)
                    p[o] += __shfl_xor(p[o], m, 64);
            float ps = p[0];
            #pragma unroll
            for (int o = 1; o < NO; ++o) ps = (lane == o) ? p[o] : ps;

            const float vn = fmaf(0.1f, ili - vli, vli);   // uses OLD i_li
            ili = fmaf(0.8f, ili, ps);
            vli = vn;
            if (lane < NO)
                out[((size_t)(g * TT + t) * NB + (bBase + wv)) * NO + lane] = vn;
        }
        __syncthreads();
    }
}

extern "C" void kernel_launch(void* const* d_in, const int* in_sizes, int n_in,
                              void* d_out, int out_size, void* d_ws, size_t ws_size,
                              hipStream_t stream)
{
    const float* x  = (const float*)d_in[0];   // [100,1024,784]
    const float* W0 = (const float*)d_in[1];   // [200,784]
    const float* b0 = (const float*)d_in[2];   // [200]
    const float* Wo = (const float*)d_in[3];   // [10,200]
    float* out = (float*)d_out;                // [100,1024,10] f32

    (void)d_ws; (void)ws_size; (void)in_sizes; (void)n_in; (void)out_size;
    fused_kernel<<<NB / BT, 256, 0, stream>>>(x, W0, b0, Wo, out);
}